// Round 2
// baseline (776.620 us; speedup 1.0000x reference)
//
#include <hip/hip_runtime.h>
#include <cstdint>

// ---------------------------------------------------------------------------
// NVFP4 fake-quant GEMM: out = fq4(x) @ fq4(w)^T + bias
// fq4: per-16-group (along K) scale = e4m3_rt(amax/6), values on e2m1 grid.
// dq = q*scale is EXACT in bf16 (<=6 significant bits) -> quantize into bf16
// buffers in d_ws, then bf16-MFMA GEMM (m97 structure).
// R2: (a) LDS subtiles stored in fragment order -> conflict-free ds_read_b128
//     (b) division-free e2m1 rounding via exact premultiplied thresholds
// ---------------------------------------------------------------------------

typedef __attribute__((ext_vector_type(8))) __bf16 bf16x8;
typedef __attribute__((ext_vector_type(4))) float f32x4;

typedef __attribute__((address_space(1))) void gvoid;
typedef __attribute__((address_space(3))) void lvoid;

// Exact fp8 e4m3fn round-trip for x >= 0, x well below 448.
// Normal range (x >= 2^-6): RNE to 3 mantissa bits via integer trick.
// Subnormal range (x < 2^-6): grid lsb is 2^-9 -> rintf (RNE) on x*512.
__device__ __forceinline__ float fp8_e4m3_rt(float x) {
    if (x < 0.015625f) {
        return __builtin_rintf(x * 512.0f) * (1.0f / 512.0f);
    }
    unsigned u = __float_as_uint(x);
    unsigned lsb = (u >> 20) & 1u;
    u = (u + 0x7FFFFu + lsb) & ~0xFFFFFu;
    return __uint_as_float(u);
}

// One thread = 4 consecutive floats; group of 16 = 4 consecutive lanes.
// Division-free: thresholds t_k = c_k*s and grid values p_k = g_k*s are
// EXACT fp32 products (c_k: <=3 sig bits, s: <=4 sig bits), so the compare
// |v| < c_k*s equals the reference's |v|/s < c_k except when the quotient
// rounds exactly onto c_k (rare, bounded perturbation << threshold).
__global__ __launch_bounds__(256) void quant_fp4(const float* __restrict__ in,
                                                 uint16_t* __restrict__ out,
                                                 int nquads) {
    int i = blockIdx.x * 256 + threadIdx.x;
    if (i >= nquads) return;
    float4 v = ((const float4*)in)[i];
    float a = fmaxf(fmaxf(fabsf(v.x), fabsf(v.y)), fmaxf(fabsf(v.z), fabsf(v.w)));
    a = fmaxf(a, __shfl_xor(a, 1));
    a = fmaxf(a, __shfl_xor(a, 2));
    float s = fp8_e4m3_rt(a / 6.0f);   // one true div per thread (exact vs ref)
    // thresholds (exact products)
    const float t0 = 0.25f * s, t1 = 0.75f * s, t2 = 1.25f * s, t3 = 1.75f * s,
                t4 = 2.5f * s, t5 = 3.5f * s, t6 = 5.0f * s;
    // dequantized grid values (exact products, <=6 sig bits -> exact bf16)
    const float p1 = 0.5f * s, p2 = s, p3 = 1.5f * s, p4 = 2.0f * s,
                p5 = 3.0f * s, p6 = 4.0f * s, p7 = 6.0f * s;
    float vals[4] = {v.x, v.y, v.z, v.w};
    unsigned r[4];
    #pragma unroll
    for (int e = 0; e < 4; ++e) {
        float x = vals[e];
        float ax = fabsf(x);
        float dq = ax < t0 ? 0.0f :
                   ax < t1 ? p1 :
                   ax < t2 ? p2 :
                   ax < t3 ? p3 :
                   ax < t4 ? p4 :
                   ax < t5 ? p5 :
                   ax < t6 ? p6 : p7;
        dq = copysignf(dq, x);
        r[e] = __float_as_uint(dq) >> 16;  // exact bf16 (low mantissa bits 0)
    }
    uint2 o;
    o.x = r[0] | (r[1] << 16);
    o.y = r[2] | (r[3] << 16);
    ((uint2*)out)[i] = o;
}

// ---------------------------------------------------------------------------
// bf16 GEMM, C[M,N] = A[M,K] * B[N,K]^T + bias. 128x128 tile, BK=32,
// 4 waves (2x2 of 64x64), 4x4 accs of v_mfma_f32_16x16x32_bf16.
//
// LDS layout: 8 subtiles per operand, each 16 rows x 32 k = 64 chunks of 16B,
// stored in FRAGMENT order: chunk index within subtile = (kchunk*16 + row).
// Staging lane L loads global chunk (row = L&15, kchunk = L>>4) and
// global_load_lds drops it at subtileBase + L*16 -- exactly fragment order.
// Fragment ds_read_b128 then reads subtileBase + lane*16: 64 lanes touch
// 1024 contiguous bytes -> zero bank conflicts.
// ---------------------------------------------------------------------------
#define BM 128
#define BN 128
#define BK 32

__global__ __launch_bounds__(256)
void gemm_w4a4(const uint16_t* __restrict__ Aq, const uint16_t* __restrict__ Bq,
               const float* __restrict__ bias, float* __restrict__ C,
               int M, int N, int K) {
    __shared__ __align__(16) uint16_t lA[BM * BK];   // 8 subtiles * 512 ushorts
    __shared__ __align__(16) uint16_t lB[BN * BK];

    const int t    = threadIdx.x;
    const int wave = t >> 6;
    const int lane = t & 63;
    const int wm   = (wave >> 1) * 64;   // wave's m offset in tile
    const int wn   = (wave & 1) * 64;    // wave's n offset in tile
    const int mBase = blockIdx.y * BM;
    const int nBase = blockIdx.x * BN;
    const int lrow = lane & 15;

    // staging addresses (invariant parts)
    const int sRow = lrow;               // row within subtile
    const int sKc  = (lane >> 4) * 8;    // k offset (ushorts) within subtile

    f32x4 acc[4][4] = {};

    for (int k0 = 0; k0 < K; k0 += BK) {
        // Wave w stages subtiles {2w, 2w+1} of both A and B.
        #pragma unroll
        for (int p = 0; p < 2; ++p) {
            const int s   = wave * 2 + p;
            const int row = s * 16 + sRow;
            const uint16_t* gA = Aq + (size_t)(mBase + row) * K + (k0 + sKc);
            const uint16_t* gB = Bq + (size_t)(nBase + row) * K + (k0 + sKc);
            __builtin_amdgcn_global_load_lds((gvoid*)gA, (lvoid*)&lA[s * 512], 16, 0, 0);
            __builtin_amdgcn_global_load_lds((gvoid*)gB, (lvoid*)&lB[s * 512], 16, 0, 0);
        }
        __syncthreads();

        // Fragments: subtile sA = 4*(wave>>1)+i, read at lane*16 B (contig).
        bf16x8 af[4], bfr[4];
        #pragma unroll
        for (int i = 0; i < 4; ++i)
            af[i] = *(const bf16x8*)&lA[((wave >> 1) * 4 + i) * 512 + lane * 8];
        #pragma unroll
        for (int j = 0; j < 4; ++j)
            bfr[j] = *(const bf16x8*)&lB[((wave & 1) * 4 + j) * 512 + lane * 8];

        #pragma unroll
        for (int i = 0; i < 4; ++i)
            #pragma unroll
            for (int j = 0; j < 4; ++j)
                acc[i][j] = __builtin_amdgcn_mfma_f32_16x16x32_bf16(
                    af[i], bfr[j], acc[i][j], 0, 0, 0);
        __syncthreads();
    }

    // Epilogue: C/D layout col = lane&15, row = (lane>>4)*4 + reg.
    const int rq = (lane >> 4) * 4;
    #pragma unroll
    for (int j = 0; j < 4; ++j) {
        const int col = nBase + wn + j * 16 + lrow;
        const float bj = bias[col];
        #pragma unroll
        for (int i = 0; i < 4; ++i) {
            const int row0 = mBase + wm + i * 16 + rq;
            #pragma unroll
            for (int r = 0; r < 4; ++r)
                C[(size_t)(row0 + r) * N + col] = acc[i][j][r] + bj;
        }
    }
}

extern "C" void kernel_launch(void* const* d_in, const int* in_sizes, int n_in,
                              void* d_out, int out_size, void* d_ws, size_t ws_size,
                              hipStream_t stream) {
    const float* x    = (const float*)d_in[0];
    const float* w    = (const float*)d_in[1];
    const float* bias = (const float*)d_in[2];
    float* out = (float*)d_out;

    const int N = in_sizes[2];            // bias length
    const int K = in_sizes[1] / N;        // weight is [N,K]
    const int M = in_sizes[0] / K;        // x is [M,K]

    uint16_t* xq = (uint16_t*)d_ws;                 // M*K bf16
    uint16_t* wq = xq + (size_t)M * K;              // N*K bf16

    const int xquads = (M * K) / 4;
    const int wquads = (N * K) / 4;
    quant_fp4<<<(xquads + 255) / 256, 256, 0, stream>>>(x, xq, xquads);
    quant_fp4<<<(wquads + 255) / 256, 256, 0, stream>>>(w, wq, wquads);

    dim3 grid(N / BN, M / BM);
    gemm_w4a4<<<grid, 256, 0, stream>>>(xq, wq, bias, out, M, N, K);
}

// Round 3
// 614.361 us; speedup vs baseline: 1.2641x; 1.2641x over previous
//
#include <hip/hip_runtime.h>
#include <cstdint>

// ---------------------------------------------------------------------------
// NVFP4 fake-quant GEMM: out = fq4(x) @ fq4(w)^T + bias
// fq4: per-16-group (along K) scale = e4m3_rt(amax/6), values on e2m1 grid.
// dq = q*scale is EXACT in bf16 (<=6 significant bits).
//
// R3: intermediate xq/wq stored in TILED layout = the GEMM's LDS fragment
// order. Block (kb = k/32, s = row/16) is 1 KiB: 64 chunks of 16 B,
// chunk = kchunk*16 + rowInSub, holding bf16 elements
//   [row = s*16+rowInSub][k = kb*32 + kchunk*8 + 0..7].
// GEMM staging then reads lane L -> base + 16*L: fully contiguous 1 KiB per
// global_load_lds (ideal coalescing, fixes R2's scatter) AND fragment
// ds_read_b128 stays conflict-free (keeps R2's zero-conflict win).
// Quant absorbs the transpose: writes lane-contiguous, reads 64-B segments.
// ---------------------------------------------------------------------------

typedef __attribute__((ext_vector_type(8))) __bf16 bf16x8;
typedef __attribute__((ext_vector_type(4))) float f32x4;

typedef __attribute__((address_space(1))) void gvoid;
typedef __attribute__((address_space(3))) void lvoid;

// Exact fp8 e4m3fn round-trip for x >= 0 (x << 448).
// Normal (x >= 2^-6): RNE to 3 mantissa bits. Subnormal: RNE on 2^-9 grid.
__device__ __forceinline__ float fp8_e4m3_rt(float x) {
    if (x < 0.015625f) {
        return __builtin_rintf(x * 512.0f) * (1.0f / 512.0f);
    }
    unsigned u = __float_as_uint(x);
    unsigned lsb = (u >> 20) & 1u;
    u = (u + 0x7FFFFu + lsb) & ~0xFFFFFu;
    return __uint_as_float(u);
}

// One thread = 4 consecutive k-elements (half a 16-B chunk) of the tiled
// layout. Group of 16 k = lanes {L, L^1, L^32, L^33} (see index derivation):
// within a (kb,s) block of 128 chunk-halves j = kchunk*32 + rowInSub*2 + half,
// wave 0 holds kchunks {0,1}, wave 1 {2,3}; the 4 partners of a 16-group are
// XOR-1 and XOR-32 apart. amax via 2 shfl_xor.
// Division-free e2m1: thresholds c_k*s and grid values g_k*s are EXACT fp32
// products (c_k <=3 sig bits, s <=4 sig bits).
__global__ __launch_bounds__(256)
void quant_fp4_tiled(const float* __restrict__ x, const float* __restrict__ w,
                     uint16_t* __restrict__ xq, uint16_t* __restrict__ wq,
                     int M, int N, int K, int xThreads) {
    int t = blockIdx.x * 256 + threadIdx.x;
    const float* in;
    uint16_t* out;
    int S16;  // number of 16-row subtiles ( = rows/16 )
    if (t < xThreads) {
        in = x; out = xq; S16 = M >> 4;
    } else {
        t -= xThreads;
        in = w; out = wq; S16 = N >> 4;
    }
    const int bi = t >> 7;           // (kb, s) block index
    const int j  = t & 127;
    const int kb = bi / S16;         // S16 is a power of two here
    const int s  = bi - kb * S16;
    const int kchunk   = j >> 5;
    const int rowInSub = (j >> 1) & 15;
    const int half     = j & 1;
    const int row = s * 16 + rowInSub;
    const int k   = kb * 32 + kchunk * 8 + half * 4;

    float4 v = *(const float4*)(in + (size_t)row * K + k);
    float a = fmaxf(fmaxf(fabsf(v.x), fabsf(v.y)), fmaxf(fabsf(v.z), fabsf(v.w)));
    a = fmaxf(a, __shfl_xor(a, 1));
    a = fmaxf(a, __shfl_xor(a, 32));
    float sc = fp8_e4m3_rt(a * (1.0f / 6.0f) == 0.0f ? 0.0f : a / 6.0f); // keep exact div
    const float t0 = 0.25f * sc, t1 = 0.75f * sc, t2 = 1.25f * sc, t3 = 1.75f * sc,
                t4 = 2.5f * sc, t5 = 3.5f * sc, t6 = 5.0f * sc;
    const float p1 = 0.5f * sc, p2 = sc, p3 = 1.5f * sc, p4 = 2.0f * sc,
                p5 = 3.0f * sc, p6 = 4.0f * sc, p7 = 6.0f * sc;
    float vals[4] = {v.x, v.y, v.z, v.w};
    unsigned r[4];
    #pragma unroll
    for (int e = 0; e < 4; ++e) {
        float xv = vals[e];
        float ax = fabsf(xv);
        float dq = ax < t0 ? 0.0f :
                   ax < t1 ? p1 :
                   ax < t2 ? p2 :
                   ax < t3 ? p3 :
                   ax < t4 ? p4 :
                   ax < t5 ? p5 :
                   ax < t6 ? p6 : p7;
        dq = copysignf(dq, xv);
        r[e] = __float_as_uint(dq) >> 16;   // exact bf16
    }
    uint2 o;
    o.x = r[0] | (r[1] << 16);
    o.y = r[2] | (r[3] << 16);
    ((uint2*)out)[t] = o;                   // lane-contiguous tiled write
}

// ---------------------------------------------------------------------------
// bf16 GEMM on tiled operands. 128x128 tile, BK=32, 4 waves (2x2 of 64x64),
// 4x4 accs of v_mfma_f32_16x16x32_bf16.
// Staging: wave w stages subtiles {2w,2w+1}; each global_load_lds is a fully
// contiguous 1 KiB (lane L -> +16L). LDS = fragment order, ds_read_b128
// conflict-free (lane L -> subtileBase + 16L).
// ---------------------------------------------------------------------------
#define BM 128
#define BN 128
#define BK 32

__global__ __launch_bounds__(256)
void gemm_w4a4(const uint16_t* __restrict__ Aq, const uint16_t* __restrict__ Bq,
               const float* __restrict__ bias, float* __restrict__ C,
               int M, int N, int K) {
    __shared__ __align__(16) uint16_t lA[BM * BK];   // 8 subtiles * 512 ushorts
    __shared__ __align__(16) uint16_t lB[BN * BK];

    const int t    = threadIdx.x;
    const int wave = t >> 6;
    const int lane = t & 63;
    const int wm   = (wave >> 1) * 64;
    const int wn   = (wave & 1) * 64;
    const int mBase = blockIdx.y * BM;
    const int nBase = blockIdx.x * BN;
    const int M16 = M >> 4, N16 = N >> 4;
    const int lrow = lane & 15;

    f32x4 acc[4][4] = {};

    for (int kb = 0; kb < (K >> 5); ++kb) {
        #pragma unroll
        for (int p = 0; p < 2; ++p) {
            const int sub = wave * 2 + p;
            const uint16_t* gA = Aq + ((size_t)kb * M16 + (mBase >> 4) + sub) * 512 + lane * 8;
            const uint16_t* gB = Bq + ((size_t)kb * N16 + (nBase >> 4) + sub) * 512 + lane * 8;
            __builtin_amdgcn_global_load_lds((gvoid*)gA, (lvoid*)&lA[sub * 512 + lane * 8], 16, 0, 0);
            __builtin_amdgcn_global_load_lds((gvoid*)gB, (lvoid*)&lB[sub * 512 + lane * 8], 16, 0, 0);
        }
        __syncthreads();

        bf16x8 af[4], bfr[4];
        #pragma unroll
        for (int i = 0; i < 4; ++i)
            af[i] = *(const bf16x8*)&lA[((wave >> 1) * 4 + i) * 512 + lane * 8];
        #pragma unroll
        for (int j = 0; j < 4; ++j)
            bfr[j] = *(const bf16x8*)&lB[((wave & 1) * 4 + j) * 512 + lane * 8];

        #pragma unroll
        for (int i = 0; i < 4; ++i)
            #pragma unroll
            for (int j = 0; j < 4; ++j)
                acc[i][j] = __builtin_amdgcn_mfma_f32_16x16x32_bf16(
                    af[i], bfr[j], acc[i][j], 0, 0, 0);
        __syncthreads();
    }

    // Epilogue: C/D layout col = lane&15, row = (lane>>4)*4 + reg.
    const int rq = (lane >> 4) * 4;
    #pragma unroll
    for (int j = 0; j < 4; ++j) {
        const int col = nBase + wn + j * 16 + lrow;
        const float bj = bias[col];
        #pragma unroll
        for (int i = 0; i < 4; ++i) {
            const int row0 = mBase + wm + i * 16 + rq;
            #pragma unroll
            for (int r = 0; r < 4; ++r)
                __builtin_nontemporal_store(acc[i][j][r] + bj,
                                            &C[(size_t)(row0 + r) * N + col]);
        }
    }
}

extern "C" void kernel_launch(void* const* d_in, const int* in_sizes, int n_in,
                              void* d_out, int out_size, void* d_ws, size_t ws_size,
                              hipStream_t stream) {
    const float* x    = (const float*)d_in[0];
    const float* w    = (const float*)d_in[1];
    const float* bias = (const float*)d_in[2];
    float* out = (float*)d_out;

    const int N = in_sizes[2];            // bias length
    const int K = in_sizes[1] / N;        // weight is [N,K]
    const int M = in_sizes[0] / K;        // x is [M,K]

    uint16_t* xq = (uint16_t*)d_ws;                 // M*K bf16, tiled
    uint16_t* wq = xq + (size_t)M * K;              // N*K bf16, tiled

    const int xThreads = (M * K) / 4;
    const int wThreads = (N * K) / 4;
    const int totThreads = xThreads + wThreads;
    quant_fp4_tiled<<<totThreads / 256, 256, 0, stream>>>(x, w, xq, wq, M, N, K, xThreads);

    dim3 grid(N / BN, M / BM);
    gemm_w4a4<<<grid, 256, 0, stream>>>(xq, wq, bias, out, M, N, K);
}